// Round 16
// baseline (1063.055 us; speedup 1.0000x reference)
//
#include <hip/hip_runtime.h>

typedef unsigned short ushort_t;
typedef short bf16x8 __attribute__((ext_vector_type(8)));
typedef float f32x4 __attribute__((ext_vector_type(4)));

#define MFMA16(a, b, c) __builtin_amdgcn_mfma_f32_16x16x32_bf16(a, b, c, 0, 0, 0)

static __device__ __forceinline__ float bf2f(ushort_t u) {
  union { unsigned int i; float f; } v;
  v.i = ((unsigned int)u) << 16;
  return v.f;
}
static __device__ __forceinline__ ushort_t f2bf(float f) {
  union { float f; unsigned int i; } v;
  v.f = f;
  unsigned int u = v.i;
  u = u + 0x7fffu + ((u >> 16) & 1u);   // round-to-nearest-even
  return (ushort_t)(u >> 16);
}
// HW packed f32->bf16 (RNE), 2 elements per instruction.
static __device__ __forceinline__ unsigned int cvtpk(float lo, float hi) {
  unsigned int r;
  asm("v_cvt_pk_bf16_f32 %0, %1, %2" : "=v"(r) : "v"(lo), "v"(hi));
  return r;
}
// async global->LDS, 16B per lane, dest = wave-uniform base + lane*16.
static __device__ __forceinline__ void gload16(const void* g, void* l) {
  __builtin_amdgcn_global_load_lds((const __attribute__((address_space(1))) void*)g,
                                   (__attribute__((address_space(3))) void*)l,
                                   16, 0, 0);
}

// ---------------------------------------------------------------- ws probe (f32)
__global__ void ws_sentinel(float* out, unsigned long long ws) {
  if (blockIdx.x == 0 && threadIdx.x == 0)
    out[0] = 1.0e6f * (1.0f + (float)(ws >> 23));   // 8MB buckets
}

// ---------------------------------------------------------------- transpose
// All three weights in one launch: f32 in[R][C] -> bf16 out[C][R].
__global__ __launch_bounds__(256) void wtrans3(const float* __restrict__ Wq,
                                               const float* __restrict__ Wkv,
                                               const float* __restrict__ Wo,
                                               ushort_t* __restrict__ WqT,
                                               ushort_t* __restrict__ WkvT,
                                               ushort_t* __restrict__ WoT) {
  int idx = blockIdx.x * 256 + threadIdx.x;
  if (idx < 262144) {                       // Wq 512x512
    int r = idx >> 9, c = idx & 511;
    WqT[c * 512 + r] = f2bf(Wq[idx]);
  } else if (idx < 786432) {                // Wkv 512x1024
    int i = idx - 262144;
    int r = i >> 10, c = i & 1023;
    WkvT[c * 512 + r] = f2bf(Wkv[i]);
  } else if (idx < 1048576) {               // Wo 512x512
    int i = idx - 786432;
    int r = i >> 9, c = i & 511;
    WoT[c * 512 + r] = f2bf(Wo[i]);
  }
}

// ---------------------------------------------------------------- GEMM
// C[M,N] = A[M,K=512] @ Bt[N,K]^T + bias[N].
// Round-13 tile/staging/swizzle mechanics + T4 counted-vmcnt 2-deep pipeline:
// double LDS buffer; per K-step wait vmcnt(LOADS) = only the OLDER tile's
// loads (newer tile stays in flight ACROSS raw s_barrier — no drain-to-0 in
// the main loop); stage tile t+2 into the just-consumed buffer after the
// post-MFMA barrier. Epilogue iteration drains vmcnt(0).
// 128x128 tile, BK=32, 4 waves. XCD-pinned 1D grid decode (Mt % 8 == 0).
template <bool AF32, bool CF32>
__global__ __launch_bounds__(256, 2) void gemm_bt(const void* __restrict__ Av,
                                                  const ushort_t* __restrict__ Bt,
                                                  const float* __restrict__ bias,
                                                  void* __restrict__ Cv,
                                                  int N, int Nt) {
  constexpr int K = 512;
  constexpr int NT = K / 32;                 // 16 K-steps
  constexpr int ABYTES = AF32 ? 128 * 32 * 4 : 128 * 32 * 2;
  __shared__ __align__(16) unsigned char As[2][ABYTES];
  __shared__ __align__(16) unsigned char Bs[2][128 * 32 * 2];
  const int t = threadIdx.x;
  const int l = t & 63;
  const int w = t >> 6;
  const int w32 = w * 32;
  const int wr = w >> 1, wc = w & 1;
  const int lrow = l & 15;
  const int g = l >> 4;

  const int bid = blockIdx.x;
  const int xcd = bid & 7;
  const int slot = bid >> 3;
  const int mt = xcd + 8 * (slot / Nt);
  const int nt = slot % Nt;
  const long m0 = (long)mt * 128;
  const int n0 = nt * 128;

  // staging lane maps (source col pre-swizzled so linear LDS = swizzled data)
  const int arow = l >> 3;                                     // f32-A: 8 rows/issue
  const int acol = ((16 * (l & 7)) ^ ((arow & 7) << 4)) >> 2;  // f32 elems
  const int brow = l >> 2;                                     // bf16: 16 rows/issue
  const int bcol = ((16 * (l & 3)) ^ ((brow & 3) << 4)) >> 1;  // bf16 elems

  auto stage = [&](int buf, int kk) {
    if constexpr (AF32) {
#pragma unroll
      for (int i = 0; i < 4; i++) {
        const float* gp = (const float*)Av + (m0 + w32 + i * 8 + arow) * (long)K + kk + acol;
        gload16(gp, &As[buf][(w32 + i * 8) * 128]);
      }
    } else {
#pragma unroll
      for (int i = 0; i < 2; i++) {
        const ushort_t* gp = (const ushort_t*)Av + (m0 + w32 + i * 16 + brow) * (long)K + kk + bcol;
        gload16(gp, &As[buf][(w32 + i * 16) * 64]);
      }
    }
#pragma unroll
    for (int i = 0; i < 2; i++) {
      const ushort_t* gp = Bt + (long)(n0 + w32 + i * 16 + brow) * K + kk + bcol;
      gload16(gp, &Bs[buf][(w32 + i * 16) * 64]);
    }
  };

  const f32x4 fz = {0.f, 0.f, 0.f, 0.f};
  f32x4 acc[4][4];
#pragma unroll
  for (int i = 0; i < 4; i++)
#pragma unroll
    for (int j = 0; j < 4; j++) acc[i][j] = fz;

  stage(0, 0);        // 6 (AF32) / 4 (bf16) loads in flight
  stage(1, 32);       // 12 / 8 in flight

#pragma unroll
  for (int ts = 0; ts < NT; ++ts) {
    const int cur = ts & 1;
    // wait ONLY the older tile's loads; keep the newer tile's in flight.
    if (ts < NT - 1) {
      if constexpr (AF32) asm volatile("s_waitcnt vmcnt(6)" ::: "memory");
      else                asm volatile("s_waitcnt vmcnt(4)" ::: "memory");
    } else {
      asm volatile("s_waitcnt vmcnt(0)" ::: "memory");   // last tile: full drain
    }
    __builtin_amdgcn_sched_barrier(0);
    __builtin_amdgcn_s_barrier();      // all waves' tile-ts loads landed
    __builtin_amdgcn_sched_barrier(0);

    bf16x8 af[4], bfr[4];
    if constexpr (AF32) {
#pragma unroll
      for (int mi = 0; mi < 4; mi++) {
        const int aR = wr * 64 + mi * 16 + lrow;
        const int s = (aR & 7) << 4;
        const int c0 = g * 32;
        f32x4 x = *(const f32x4*)&As[cur][aR * 128 + (c0 ^ s)];
        f32x4 y = *(const f32x4*)&As[cur][aR * 128 + ((c0 + 16) ^ s)];
        union { unsigned int u[4]; bf16x8 v; } r;
        r.u[0] = cvtpk(x[0], x[1]);
        r.u[1] = cvtpk(x[2], x[3]);
        r.u[2] = cvtpk(y[0], y[1]);
        r.u[3] = cvtpk(y[2], y[3]);
        af[mi] = r.v;
      }
    } else {
#pragma unroll
      for (int mi = 0; mi < 4; mi++) {
        const int aR = wr * 64 + mi * 16 + lrow;
        af[mi] = *(const bf16x8*)&As[cur][aR * 64 + ((g * 16) ^ ((aR & 3) << 4))];
      }
    }
#pragma unroll
    for (int ni = 0; ni < 4; ni++) {
      const int bR = wc * 64 + ni * 16 + lrow;
      bfr[ni] = *(const bf16x8*)&Bs[cur][bR * 64 + ((g * 16) ^ ((bR & 3) << 4))];
    }
#pragma unroll
    for (int mi = 0; mi < 4; mi++)
#pragma unroll
      for (int ni = 0; ni < 4; ni++)
        acc[mi][ni] = MFMA16(af[mi], bfr[ni], acc[mi][ni]);

    __builtin_amdgcn_sched_barrier(0);
    __builtin_amdgcn_s_barrier();      // all waves consumed buf[cur]
    __builtin_amdgcn_sched_barrier(0);
    asm volatile("" ::: "memory");
    if (ts + 2 < NT) stage(cur, (ts + 2) * 32);   // refill consumed buffer
  }

#pragma unroll
  for (int mi = 0; mi < 4; mi++) {
    const long row0 = m0 + wr * 64 + mi * 16 + (l >> 4) * 4;
#pragma unroll
    for (int ni = 0; ni < 4; ni++) {
      const int col = n0 + wc * 64 + ni * 16 + lrow;
      const float bv = bias[col];
#pragma unroll
      for (int r = 0; r < 4; r++) {
        const float val = acc[mi][ni][r] + bv;
        if constexpr (CF32)
          ((float*)Cv)[(row0 + r) * N + col] = val;
        else
          ((ushort_t*)Cv)[(row0 + r) * N + col] = f2bf(val);
      }
    }
  }
}

// ---------------------------------------------------------------- attention
// Round-13 proven state: 4 waves per (window, head); wave w owns q-row block
// mi=w. K staged ONCE into LDS via gload16; Ks unions with Vt. ~27 KB/block.
__global__ __launch_bounds__(256, 1) void attn_k(const ushort_t* __restrict__ Qp,
                                                 const ushort_t* __restrict__ KVp,
                                                 const float* __restrict__ rpbt,
                                                 ushort_t* __restrict__ Ao) {
  __shared__ ushort_t P[64 * 136];                              // probabilities, bf16
  __shared__ __align__(16) unsigned char poolKV[32 * 136 * 2];  // Ks then Vt
  __shared__ float Ltab[225];                                   // rpb column for head
  ushort_t* Ks = (ushort_t*)poolKV;   // [128][32] u16 linear (8,192 B)
  ushort_t* Vt = (ushort_t*)poolKV;   // [32][136] u16 (8,704 B)
  const int t = threadIdx.x;
  const int l = t & 63;
  const int w = t >> 6;              // wave = owned mi block
  const int wnd = blockIdx.x;        // chunk-local (b, wh, ww)
  const int h = blockIdx.y;          // 0..15
  const int b = wnd >> 8;
  const int wh = (wnd >> 4) & 15;
  const int ww = wnd & 15;

  const int lrow = l & 15;
  const int lq = l >> 4;
  const int lk = lq * 8;

  auto qrow = [&](int q) -> long {
    int i = q >> 3, j = q & 7;
    int ho = (wh * 8 + i + 4) & 127;     // un-roll: rolled pos p <- orig p+shift
    int wo = (ww * 8 + j + 4) & 127;
    return (long)((b << 14) + (ho << 7) + wo);
  };
  auto kvrow = [&](int kp) -> long {
    int f = kp >> 6, m = kp & 63;
    int i = m >> 3, j = m & 7;
    int ho = (wh * 8 + i + 4) & 127;
    int wo = (ww * 8 + j + 4) & 127;
    return (long)(((b * 2 + f) << 14) + (ho << 7) + wo);
  };
  auto cnt_of = [&](int m) -> int {
    int hr = wh * 8 + (m >> 3), wr2 = ww * 8 + (m & 7);
    int rh = hr < 120 ? 0 : (hr < 124 ? 1 : 2);
    int rw = wr2 < 120 ? 0 : (wr2 < 124 ? 1 : 2);
    return rh * 3 + rw;
  };
  auto cvec = [](int m) -> int { return 15 * (m >> 3) + (m & 7); };

  // ---- stage K into LDS: wave w covers rows w*32..w*32+31 (2 issues)
#pragma unroll
  for (int i = 0; i < 2; i++) {
    const int row = w * 32 + i * 16 + (l >> 2);
    const ushort_t* gp = KVp + kvrow(row) * 1024 + h * 32 + (l & 3) * 8;
    gload16(gp, Ks + (w * 32 + i * 16) * 32);
  }
  for (int i = t; i < 225; i += 256) Ltab[i] = rpbt[i * 16 + h];

  // ---- Q fragment (global, read once)
  bf16x8 af = *(const bf16x8*)(Qp + qrow(w * 16 + lrow) * 512 + h * 32 + lk);

  __syncthreads();  // K staged (vmcnt drained) + Ltab ready

  // ---- QK^T for own row block, K from LDS
  const f32x4 fz = {0.f, 0.f, 0.f, 0.f};
  f32x4 s[8];
#pragma unroll
  for (int ni = 0; ni < 8; ni++) s[ni] = fz;
#pragma unroll
  for (int ni = 0; ni < 8; ni++) {
    bf16x8 kf = *(const bf16x8*)&Ks[(ni * 16 + lrow) * 32 + lk];
    s[ni] = MFMA16(af, kf, s[ni]);
  }

  // ---- scale + rpb + mask + wave-parallel softmax (16-lane groups own rows)
  const float scale = 0.17677669529663687f;  // 32^-0.5
#pragma unroll
  for (int r = 0; r < 4; r++) {
    const int q = w * 16 + lq * 4 + r;
    const int cq = cnt_of(q);
    const int cqv = cvec(q);
    float mx = -3.0e38f;
#pragma unroll
    for (int ni = 0; ni < 8; ni++) {
      const int k63 = (ni * 16 + lrow) & 63;
      float v = s[ni][r] * scale + Ltab[cqv + cvec(63 - k63)];
      if (cnt_of(k63) != cq) v -= 100.f;
      s[ni][r] = v;
      mx = fmaxf(mx, v);
    }
    mx = fmaxf(mx, __shfl_xor(mx, 1));
    mx = fmaxf(mx, __shfl_xor(mx, 2));
    mx = fmaxf(mx, __shfl_xor(mx, 4));
    mx = fmaxf(mx, __shfl_xor(mx, 8));
    float sum = 0.f;
#pragma unroll
    for (int ni = 0; ni < 8; ni++) {
      float p = __expf(s[ni][r] - mx);
      s[ni][r] = p;
      sum += p;
    }
    sum += __shfl_xor(sum, 1);
    sum += __shfl_xor(sum, 2);
    sum += __shfl_xor(sum, 4);
    sum += __shfl_xor(sum, 8);
    const float inv = 1.f / sum;
#pragma unroll
    for (int ni = 0; ni < 8; ni++)
      P[q * 136 + ni * 16 + lrow] = f2bf(s[ni][r] * inv);
  }

  __syncthreads();  // Ks + Ltab dead across ALL waves; pool reusable as Vt

  // ---- stage V transposed: Vt[d][kvpos]; thread t covers (kp = t&127, d-half)
  {
    const int kp = t & 127;
    const int dh = t >> 7;       // 0: d 0..15, 1: d 16..31
    const ushort_t* src = KVp + kvrow(kp) * 1024 + 512 + h * 32 + dh * 16;
    bf16x8 v0 = *(const bf16x8*)(src);
    bf16x8 v1 = *(const bf16x8*)(src + 8);
#pragma unroll
    for (int d = 0; d < 8; d++) {
      Vt[(dh * 16 + d) * 136 + kp] = (ushort_t)v0[d];
      Vt[(dh * 16 + 8 + d) * 136 + kp] = (ushort_t)v1[d];
    }
  }
  __syncthreads();  // Vt ready (P own-rows need no barrier: self-written)

  // ---- PV for own row block: O[16x32] = P[16x128] @ V[128x32]
  f32x4 o[2] = {fz, fz};
#pragma unroll
  for (int ks = 0; ks < 4; ks++) {
    bf16x8 pf = *(const bf16x8*)&P[(w * 16 + lrow) * 136 + ks * 32 + lk];
#pragma unroll
    for (int ni = 0; ni < 2; ni++) {
      bf16x8 vf = *(const bf16x8*)&Vt[(ni * 16 + lrow) * 136 + ks * 32 + lk];
      o[ni] = MFMA16(pf, vf, o[ni]);
    }
  }

  // ---- write Ao (spatial order restored by qrow mapping)
#pragma unroll
  for (int ni = 0; ni < 2; ni++)
#pragma unroll
    for (int r = 0; r < 4; r++) {
      const int q = w * 16 + lq * 4 + r;
      Ao[qrow(q) * 512 + h * 32 + ni * 16 + lrow] = f2bf(o[ni][r]);
    }
}

// ---------------------------------------------------------------- launch
extern "C" void kernel_launch(void* const* d_in, const int* in_sizes, int n_in,
                              void* d_out, int out_size, void* d_ws, size_t ws_size,
                              hipStream_t stream) {
  (void)in_sizes; (void)n_in; (void)out_size;
  const float* q    = (const float*)d_in[0];   // f32 inputs
  const float* kv   = (const float*)d_in[1];
  // d_in[2], d_in[3] = H, W (constants 128, hardcoded)
  const float* rpbt = (const float*)d_in[4];
  const float* Wq   = (const float*)d_in[5];
  const float* bq   = (const float*)d_in[6];
  const float* Wkv  = (const float*)d_in[7];
  const float* bkv  = (const float*)d_in[8];
  const float* Wo   = (const float*)d_in[9];
  const float* bo   = (const float*)d_in[10];
  float* out = (float*)d_out;                  // f32 output

  const size_t QB  = 16384ULL * 512;    // Q/Ao elements per batch
  const size_t KVB = 32768ULL * 1024;   // projected KV elements per batch
  const size_t per_b_bytes = (QB + QB + KVB) * 2;   // bf16 scratch
  const size_t fixed_bytes = (512ULL*512 + 512ULL*1024 + 512ULL*512) * 2; // 2 MB
  const size_t needed1 = fixed_bytes + per_b_bytes;

  if (ws_size < needed1) {   // can't run: signal ws_size via out[0]
    ws_sentinel<<<dim3(1), 64, 0, stream>>>(out, (unsigned long long)ws_size);
    return;
  }

  int nbc = 8;
  while (nbc > 1 && fixed_bytes + (size_t)nbc * per_b_bytes > ws_size) nbc >>= 1;

  char* ws = (char*)d_ws;
  ushort_t* WqT  = (ushort_t*)ws;
  ushort_t* WkvT = WqT + 512 * 512;
  ushort_t* WoT  = WkvT + 512 * 1024;
  ushort_t* Qp   = (ushort_t*)(ws + fixed_bytes);
  ushort_t* Ao   = Qp + (size_t)nbc * QB;
  ushort_t* KVp  = Ao + (size_t)nbc * QB;

  wtrans3<<<dim3(4096), 256, 0, stream>>>(Wq, Wkv, Wo, WqT, WkvT, WoT);

  for (int c = 0; c < 8 / nbc; ++c) {
    const size_t b0 = (size_t)c * nbc;
    const int MtQ = nbc * 128;    // Q/Ao M-tiles, divisible by 8
    const int MtKV = nbc * 256;   // KV M-tiles, divisible by 8
    gemm_bt<true, false><<<dim3(MtQ * 4), 256, 0, stream>>>(q + b0 * QB, WqT, bq,
                                                            Qp, 512, 4);
    gemm_bt<true, false><<<dim3(MtKV * 8), 256, 0, stream>>>(kv + b0 * KVB / 2, WkvT,
                                                             bkv, KVp, 1024, 8);
    attn_k<<<dim3(nbc * 256, 16), 256, 0, stream>>>(Qp, KVp, rpbt, Ao);
    gemm_bt<false, true><<<dim3(MtQ * 4), 256, 0, stream>>>(Ao, WoT, bo,
                                                            out + b0 * QB, 512, 4);
  }
}

// Round 17
// 1037.451 us; speedup vs baseline: 1.0247x; 1.0247x over previous
//
#include <hip/hip_runtime.h>

typedef unsigned short ushort_t;
typedef short bf16x8 __attribute__((ext_vector_type(8)));
typedef float f32x4 __attribute__((ext_vector_type(4)));

#define MFMA16(a, b, c) __builtin_amdgcn_mfma_f32_16x16x32_bf16(a, b, c, 0, 0, 0)

static __device__ __forceinline__ float bf2f(ushort_t u) {
  union { unsigned int i; float f; } v;
  v.i = ((unsigned int)u) << 16;
  return v.f;
}
static __device__ __forceinline__ ushort_t f2bf(float f) {
  union { float f; unsigned int i; } v;
  v.f = f;
  unsigned int u = v.i;
  u = u + 0x7fffu + ((u >> 16) & 1u);   // round-to-nearest-even
  return (ushort_t)(u >> 16);
}
// HW packed f32->bf16 (RNE), 2 elements per instruction.
static __device__ __forceinline__ unsigned int cvtpk(float lo, float hi) {
  unsigned int r;
  asm("v_cvt_pk_bf16_f32 %0, %1, %2" : "=v"(r) : "v"(lo), "v"(hi));
  return r;
}
// async global->LDS, 16B per lane, dest = wave-uniform base + lane*16.
static __device__ __forceinline__ void gload16(const void* g, void* l) {
  __builtin_amdgcn_global_load_lds((const __attribute__((address_space(1))) void*)g,
                                   (__attribute__((address_space(3))) void*)l,
                                   16, 0, 0);
}

// ---------------------------------------------------------------- ws probe (f32)
__global__ void ws_sentinel(float* out, unsigned long long ws) {
  if (blockIdx.x == 0 && threadIdx.x == 0)
    out[0] = 1.0e6f * (1.0f + (float)(ws >> 23));   // 8MB buckets
}

// ---------------------------------------------------------------- transpose
// All three weights in one launch: f32 in[R][C] -> bf16 out[C][R].
__global__ __launch_bounds__(256) void wtrans3(const float* __restrict__ Wq,
                                               const float* __restrict__ Wkv,
                                               const float* __restrict__ Wo,
                                               ushort_t* __restrict__ WqT,
                                               ushort_t* __restrict__ WkvT,
                                               ushort_t* __restrict__ WoT) {
  int idx = blockIdx.x * 256 + threadIdx.x;
  if (idx < 262144) {                       // Wq 512x512
    int r = idx >> 9, c = idx & 511;
    WqT[c * 512 + r] = f2bf(Wq[idx]);
  } else if (idx < 786432) {                // Wkv 512x1024
    int i = idx - 262144;
    int r = i >> 10, c = i & 1023;
    WkvT[c * 512 + r] = f2bf(Wkv[i]);
  } else if (idx < 1048576) {               // Wo 512x512
    int i = idx - 786432;
    int r = i >> 9, c = i & 511;
    WoT[c * 512 + r] = f2bf(Wo[i]);
  }
}

// ---------------------------------------------------------------- GEMM
// Round-13 proven optimum (505-508 us KV): global_load_lds(16B) staging,
// single LDS buffer, 2 barriers/K-step, XOR swizzle both sides.
// 128x128 tile, BK=32, 4 waves. XCD-pinned 1D grid decode (Mt % 8 == 0).
template <bool AF32, bool CF32>
__global__ __launch_bounds__(256, 2) void gemm_bt(const void* __restrict__ Av,
                                                  const ushort_t* __restrict__ Bt,
                                                  const float* __restrict__ bias,
                                                  void* __restrict__ Cv,
                                                  int N, int Nt) {
  constexpr int K = 512;
  __shared__ __align__(16) unsigned char As[AF32 ? 128 * 32 * 4 : 128 * 32 * 2];
  __shared__ __align__(16) unsigned char Bs[128 * 32 * 2];
  const int t = threadIdx.x;
  const int l = t & 63;
  const int w = t >> 6;
  const int w32 = w * 32;
  const int wr = w >> 1, wc = w & 1;
  const int lrow = l & 15;
  const int g = l >> 4;

  const int bid = blockIdx.x;
  const int xcd = bid & 7;
  const int slot = bid >> 3;
  const int mt = xcd + 8 * (slot / Nt);
  const int nt = slot % Nt;
  const long m0 = (long)mt * 128;
  const int n0 = nt * 128;

  // staging lane maps (source col pre-swizzled so linear LDS = swizzled data)
  const int arow = l >> 3;                                     // f32-A: 8 rows/issue
  const int acol = ((16 * (l & 7)) ^ ((arow & 7) << 4)) >> 2;  // f32 elems
  const int brow = l >> 2;                                     // bf16: 16 rows/issue
  const int bcol = ((16 * (l & 3)) ^ ((brow & 3) << 4)) >> 1;  // bf16 elems

  const f32x4 fz = {0.f, 0.f, 0.f, 0.f};
  f32x4 acc[4][4];
#pragma unroll
  for (int i = 0; i < 4; i++)
#pragma unroll
    for (int j = 0; j < 4; j++) acc[i][j] = fz;

  for (int kk = 0; kk < K; kk += 32) {
    __syncthreads();   // previous iteration's LDS reads complete
    if constexpr (AF32) {
#pragma unroll
      for (int i = 0; i < 4; i++) {
        const float* gp = (const float*)Av + (m0 + w32 + i * 8 + arow) * (long)K + kk + acol;
        gload16(gp, &As[(w32 + i * 8) * 128]);
      }
    } else {
#pragma unroll
      for (int i = 0; i < 2; i++) {
        const ushort_t* gp = (const ushort_t*)Av + (m0 + w32 + i * 16 + brow) * (long)K + kk + bcol;
        gload16(gp, &As[(w32 + i * 16) * 64]);
      }
    }
#pragma unroll
    for (int i = 0; i < 2; i++) {
      const ushort_t* gp = Bt + (long)(n0 + w32 + i * 16 + brow) * K + kk + bcol;
      gload16(gp, &Bs[(w32 + i * 16) * 64]);
    }
    __syncthreads();   // vmcnt(0) drain + barrier: tile visible

    bf16x8 af[4], bfr[4];
    if constexpr (AF32) {
#pragma unroll
      for (int mi = 0; mi < 4; mi++) {
        const int aR = wr * 64 + mi * 16 + lrow;
        const int s = (aR & 7) << 4;
        const int c0 = g * 32;
        f32x4 x = *(const f32x4*)&As[aR * 128 + (c0 ^ s)];
        f32x4 y = *(const f32x4*)&As[aR * 128 + ((c0 + 16) ^ s)];
        union { unsigned int u[4]; bf16x8 v; } r;
        r.u[0] = cvtpk(x[0], x[1]);
        r.u[1] = cvtpk(x[2], x[3]);
        r.u[2] = cvtpk(y[0], y[1]);
        r.u[3] = cvtpk(y[2], y[3]);
        af[mi] = r.v;
      }
    } else {
#pragma unroll
      for (int mi = 0; mi < 4; mi++) {
        const int aR = wr * 64 + mi * 16 + lrow;
        af[mi] = *(const bf16x8*)&As[aR * 64 + ((g * 16) ^ ((aR & 3) << 4))];
      }
    }
#pragma unroll
    for (int ni = 0; ni < 4; ni++) {
      const int bR = wc * 64 + ni * 16 + lrow;
      bfr[ni] = *(const bf16x8*)&Bs[bR * 64 + ((g * 16) ^ ((bR & 3) << 4))];
    }
#pragma unroll
    for (int mi = 0; mi < 4; mi++)
#pragma unroll
      for (int ni = 0; ni < 4; ni++)
        acc[mi][ni] = MFMA16(af[mi], bfr[ni], acc[mi][ni]);
  }

#pragma unroll
  for (int mi = 0; mi < 4; mi++) {
    const long row0 = m0 + wr * 64 + mi * 16 + (l >> 4) * 4;
#pragma unroll
    for (int ni = 0; ni < 4; ni++) {
      const int col = n0 + wc * 64 + ni * 16 + lrow;
      const float bv = bias[col];
#pragma unroll
      for (int r = 0; r < 4; r++) {
        const float val = acc[mi][ni][r] + bv;
        if constexpr (CF32)
          ((float*)Cv)[(row0 + r) * N + col] = val;
        else
          ((ushort_t*)Cv)[(row0 + r) * N + col] = f2bf(val);
      }
    }
  }
}

// ---------------------------------------------------------------- attention
// Round-13 proven state: 4 waves per (window, head); wave w owns q-row block
// mi=w. K staged ONCE into LDS via gload16; Ks unions with Vt. ~27 KB/block.
__global__ __launch_bounds__(256, 1) void attn_k(const ushort_t* __restrict__ Qp,
                                                 const ushort_t* __restrict__ KVp,
                                                 const float* __restrict__ rpbt,
                                                 ushort_t* __restrict__ Ao) {
  __shared__ ushort_t P[64 * 136];                              // probabilities, bf16
  __shared__ __align__(16) unsigned char poolKV[32 * 136 * 2];  // Ks then Vt
  __shared__ float Ltab[225];                                   // rpb column for head
  ushort_t* Ks = (ushort_t*)poolKV;   // [128][32] u16 linear (8,192 B)
  ushort_t* Vt = (ushort_t*)poolKV;   // [32][136] u16 (8,704 B)
  const int t = threadIdx.x;
  const int l = t & 63;
  const int w = t >> 6;              // wave = owned mi block
  const int wnd = blockIdx.x;        // chunk-local (b, wh, ww)
  const int h = blockIdx.y;          // 0..15
  const int b = wnd >> 8;
  const int wh = (wnd >> 4) & 15;
  const int ww = wnd & 15;

  const int lrow = l & 15;
  const int lq = l >> 4;
  const int lk = lq * 8;

  auto qrow = [&](int q) -> long {
    int i = q >> 3, j = q & 7;
    int ho = (wh * 8 + i + 4) & 127;     // un-roll: rolled pos p <- orig p+shift
    int wo = (ww * 8 + j + 4) & 127;
    return (long)((b << 14) + (ho << 7) + wo);
  };
  auto kvrow = [&](int kp) -> long {
    int f = kp >> 6, m = kp & 63;
    int i = m >> 3, j = m & 7;
    int ho = (wh * 8 + i + 4) & 127;
    int wo = (ww * 8 + j + 4) & 127;
    return (long)(((b * 2 + f) << 14) + (ho << 7) + wo);
  };
  auto cnt_of = [&](int m) -> int {
    int hr = wh * 8 + (m >> 3), wr2 = ww * 8 + (m & 7);
    int rh = hr < 120 ? 0 : (hr < 124 ? 1 : 2);
    int rw = wr2 < 120 ? 0 : (wr2 < 124 ? 1 : 2);
    return rh * 3 + rw;
  };
  auto cvec = [](int m) -> int { return 15 * (m >> 3) + (m & 7); };

  // ---- stage K into LDS: wave w covers rows w*32..w*32+31 (2 issues)
#pragma unroll
  for (int i = 0; i < 2; i++) {
    const int row = w * 32 + i * 16 + (l >> 2);
    const ushort_t* gp = KVp + kvrow(row) * 1024 + h * 32 + (l & 3) * 8;
    gload16(gp, Ks + (w * 32 + i * 16) * 32);
  }
  for (int i = t; i < 225; i += 256) Ltab[i] = rpbt[i * 16 + h];

  // ---- Q fragment (global, read once)
  bf16x8 af = *(const bf16x8*)(Qp + qrow(w * 16 + lrow) * 512 + h * 32 + lk);

  __syncthreads();  // K staged (vmcnt drained) + Ltab ready

  // ---- QK^T for own row block, K from LDS
  const f32x4 fz = {0.f, 0.f, 0.f, 0.f};
  f32x4 s[8];
#pragma unroll
  for (int ni = 0; ni < 8; ni++) s[ni] = fz;
#pragma unroll
  for (int ni = 0; ni < 8; ni++) {
    bf16x8 kf = *(const bf16x8*)&Ks[(ni * 16 + lrow) * 32 + lk];
    s[ni] = MFMA16(af, kf, s[ni]);
  }

  // ---- scale + rpb + mask + wave-parallel softmax (16-lane groups own rows)
  const float scale = 0.17677669529663687f;  // 32^-0.5
#pragma unroll
  for (int r = 0; r < 4; r++) {
    const int q = w * 16 + lq * 4 + r;
    const int cq = cnt_of(q);
    const int cqv = cvec(q);
    float mx = -3.0e38f;
#pragma unroll
    for (int ni = 0; ni < 8; ni++) {
      const int k63 = (ni * 16 + lrow) & 63;
      float v = s[ni][r] * scale + Ltab[cqv + cvec(63 - k63)];
      if (cnt_of(k63) != cq) v -= 100.f;
      s[ni][r] = v;
      mx = fmaxf(mx, v);
    }
    mx = fmaxf(mx, __shfl_xor(mx, 1));
    mx = fmaxf(mx, __shfl_xor(mx, 2));
    mx = fmaxf(mx, __shfl_xor(mx, 4));
    mx = fmaxf(mx, __shfl_xor(mx, 8));
    float sum = 0.f;
#pragma unroll
    for (int ni = 0; ni < 8; ni++) {
      float p = __expf(s[ni][r] - mx);
      s[ni][r] = p;
      sum += p;
    }
    sum += __shfl_xor(sum, 1);
    sum += __shfl_xor(sum, 2);
    sum += __shfl_xor(sum, 4);
    sum += __shfl_xor(sum, 8);
    const float inv = 1.f / sum;
#pragma unroll
    for (int ni = 0; ni < 8; ni++)
      P[q * 136 + ni * 16 + lrow] = f2bf(s[ni][r] * inv);
  }

  __syncthreads();  // Ks + Ltab dead across ALL waves; pool reusable as Vt

  // ---- stage V transposed: Vt[d][kvpos]; thread t covers (kp = t&127, d-half)
  {
    const int kp = t & 127;
    const int dh = t >> 7;       // 0: d 0..15, 1: d 16..31
    const ushort_t* src = KVp + kvrow(kp) * 1024 + 512 + h * 32 + dh * 16;
    bf16x8 v0 = *(const bf16x8*)(src);
    bf16x8 v1 = *(const bf16x8*)(src + 8);
#pragma unroll
    for (int d = 0; d < 8; d++) {
      Vt[(dh * 16 + d) * 136 + kp] = (ushort_t)v0[d];
      Vt[(dh * 16 + 8 + d) * 136 + kp] = (ushort_t)v1[d];
    }
  }
  __syncthreads();  // Vt ready (P own-rows need no barrier: self-written)

  // ---- PV for own row block: O[16x32] = P[16x128] @ V[128x32]
  f32x4 o[2] = {fz, fz};
#pragma unroll
  for (int ks = 0; ks < 4; ks++) {
    bf16x8 pf = *(const bf16x8*)&P[(w * 16 + lrow) * 136 + ks * 32 + lk];
#pragma unroll
    for (int ni = 0; ni < 2; ni++) {
      bf16x8 vf = *(const bf16x8*)&Vt[(ni * 16 + lrow) * 136 + ks * 32 + lk];
      o[ni] = MFMA16(pf, vf, o[ni]);
    }
  }

  // ---- write Ao (spatial order restored by qrow mapping)
#pragma unroll
  for (int ni = 0; ni < 2; ni++)
#pragma unroll
    for (int r = 0; r < 4; r++) {
      const int q = w * 16 + lq * 4 + r;
      Ao[qrow(q) * 512 + h * 32 + ni * 16 + lrow] = f2bf(o[ni][r]);
    }
}

// ---------------------------------------------------------------- launch
// nbc=2: per-chunk producer->consumer working set (KVp 134 MB + Qp 67 MB +
// Ao 67 MB) fits the 256 MB L3, so attn/O-proj read from Infinity Cache
// instead of HBM. Kernels unchanged (round-13 proven).
extern "C" void kernel_launch(void* const* d_in, const int* in_sizes, int n_in,
                              void* d_out, int out_size, void* d_ws, size_t ws_size,
                              hipStream_t stream) {
  (void)in_sizes; (void)n_in; (void)out_size;
  const float* q    = (const float*)d_in[0];   // f32 inputs
  const float* kv   = (const float*)d_in[1];
  // d_in[2], d_in[3] = H, W (constants 128, hardcoded)
  const float* rpbt = (const float*)d_in[4];
  const float* Wq   = (const float*)d_in[5];
  const float* bq   = (const float*)d_in[6];
  const float* Wkv  = (const float*)d_in[7];
  const float* bkv  = (const float*)d_in[8];
  const float* Wo   = (const float*)d_in[9];
  const float* bo   = (const float*)d_in[10];
  float* out = (float*)d_out;                  // f32 output

  const size_t QB  = 16384ULL * 512;    // Q/Ao elements per batch
  const size_t KVB = 32768ULL * 1024;   // projected KV elements per batch
  const size_t per_b_bytes = (QB + QB + KVB) * 2;   // bf16 scratch
  const size_t fixed_bytes = (512ULL*512 + 512ULL*1024 + 512ULL*512) * 2; // 2 MB
  const size_t needed1 = fixed_bytes + per_b_bytes;

  if (ws_size < needed1) {   // can't run: signal ws_size via out[0]
    ws_sentinel<<<dim3(1), 64, 0, stream>>>(out, (unsigned long long)ws_size);
    return;
  }

  // L3-resident chunking: prefer nbc=2; fall back to 1 if ws is tiny.
  int nbc = 2;
  while (nbc > 1 && fixed_bytes + (size_t)nbc * per_b_bytes > ws_size) nbc >>= 1;

  char* ws = (char*)d_ws;
  ushort_t* WqT  = (ushort_t*)ws;
  ushort_t* WkvT = WqT + 512 * 512;
  ushort_t* WoT  = WkvT + 512 * 1024;
  ushort_t* Qp   = (ushort_t*)(ws + fixed_bytes);
  ushort_t* Ao   = Qp + (size_t)nbc * QB;
  ushort_t* KVp  = Ao + (size_t)nbc * QB;

  wtrans3<<<dim3(4096), 256, 0, stream>>>(Wq, Wkv, Wo, WqT, WkvT, WoT);

  for (int c = 0; c < 8 / nbc; ++c) {
    const size_t b0 = (size_t)c * nbc;
    const int MtQ = nbc * 128;    // Q/Ao M-tiles, divisible by 8
    const int MtKV = nbc * 256;   // KV M-tiles, divisible by 8
    gemm_bt<true, false><<<dim3(MtQ * 4), 256, 0, stream>>>(q + b0 * QB, WqT, bq,
                                                            Qp, 512, 4);
    gemm_bt<true, false><<<dim3(MtKV * 8), 256, 0, stream>>>(kv + b0 * KVB / 2, WkvT,
                                                             bkv, KVp, 1024, 8);
    attn_k<<<dim3(nbc * 256, 16), 256, 0, stream>>>(Qp, KVp, rpbt, Ao);
    gemm_bt<false, true><<<dim3(MtQ * 4), 256, 0, stream>>>(Ao, WoT, bo,
                                                            out + b0 * QB, 512, 4);
  }
}

// Round 18
// 1022.413 us; speedup vs baseline: 1.0398x; 1.0147x over previous
//
#include <hip/hip_runtime.h>

typedef unsigned short ushort_t;
typedef short bf16x8 __attribute__((ext_vector_type(8)));
typedef float f32x4 __attribute__((ext_vector_type(4)));

#define MFMA16(a, b, c) __builtin_amdgcn_mfma_f32_16x16x32_bf16(a, b, c, 0, 0, 0)

static __device__ __forceinline__ float bf2f(ushort_t u) {
  union { unsigned int i; float f; } v;
  v.i = ((unsigned int)u) << 16;
  return v.f;
}
static __device__ __forceinline__ ushort_t f2bf(float f) {
  union { float f; unsigned int i; } v;
  v.f = f;
  unsigned int u = v.i;
  u = u + 0x7fffu + ((u >> 16) & 1u);   // round-to-nearest-even
  return (ushort_t)(u >> 16);
}
// HW packed f32->bf16 (RNE), 2 elements per instruction.
static __device__ __forceinline__ unsigned int cvtpk(float lo, float hi) {
  unsigned int r;
  asm("v_cvt_pk_bf16_f32 %0, %1, %2" : "=v"(r) : "v"(lo), "v"(hi));
  return r;
}
// async global->LDS, 16B per lane, dest = wave-uniform base + lane*16.
static __device__ __forceinline__ void gload16(const void* g, void* l) {
  __builtin_amdgcn_global_load_lds((const __attribute__((address_space(1))) void*)g,
                                   (__attribute__((address_space(3))) void*)l,
                                   16, 0, 0);
}

// ---------------------------------------------------------------- ws probe (f32)
__global__ void ws_sentinel(float* out, unsigned long long ws) {
  if (blockIdx.x == 0 && threadIdx.x == 0)
    out[0] = 1.0e6f * (1.0f + (float)(ws >> 23));   // 8MB buckets
}

// ---------------------------------------------------------------- transpose
// All three weights in one launch: f32 in[R][C] -> bf16 out[C][R].
__global__ __launch_bounds__(256) void wtrans3(const float* __restrict__ Wq,
                                               const float* __restrict__ Wkv,
                                               const float* __restrict__ Wo,
                                               ushort_t* __restrict__ WqT,
                                               ushort_t* __restrict__ WkvT,
                                               ushort_t* __restrict__ WoT) {
  int idx = blockIdx.x * 256 + threadIdx.x;
  if (idx < 262144) {                       // Wq 512x512
    int r = idx >> 9, c = idx & 511;
    WqT[c * 512 + r] = f2bf(Wq[idx]);
  } else if (idx < 786432) {                // Wkv 512x1024
    int i = idx - 262144;
    int r = i >> 10, c = i & 1023;
    WkvT[c * 512 + r] = f2bf(Wkv[i]);
  } else if (idx < 1048576) {               // Wo 512x512
    int i = idx - 786432;
    int r = i >> 9, c = i & 511;
    WoT[c * 512 + r] = f2bf(Wo[i]);
  }
}

// ---------------------------------------------------------------- GEMM
// Round-13 proven optimum (505-508 us KV): global_load_lds(16B) staging,
// single LDS buffer, 2 barriers/K-step, XOR swizzle both sides.
// 128x128 tile, BK=32, 4 waves. XCD-pinned 1D grid decode (Mt % 8 == 0).
template <bool AF32, bool CF32>
__global__ __launch_bounds__(256, 2) void gemm_bt(const void* __restrict__ Av,
                                                  const ushort_t* __restrict__ Bt,
                                                  const float* __restrict__ bias,
                                                  void* __restrict__ Cv,
                                                  int N, int Nt) {
  constexpr int K = 512;
  __shared__ __align__(16) unsigned char As[AF32 ? 128 * 32 * 4 : 128 * 32 * 2];
  __shared__ __align__(16) unsigned char Bs[128 * 32 * 2];
  const int t = threadIdx.x;
  const int l = t & 63;
  const int w = t >> 6;
  const int w32 = w * 32;
  const int wr = w >> 1, wc = w & 1;
  const int lrow = l & 15;
  const int g = l >> 4;

  const int bid = blockIdx.x;
  const int xcd = bid & 7;
  const int slot = bid >> 3;
  const int mt = xcd + 8 * (slot / Nt);
  const int nt = slot % Nt;
  const long m0 = (long)mt * 128;
  const int n0 = nt * 128;

  // staging lane maps (source col pre-swizzled so linear LDS = swizzled data)
  const int arow = l >> 3;                                     // f32-A: 8 rows/issue
  const int acol = ((16 * (l & 7)) ^ ((arow & 7) << 4)) >> 2;  // f32 elems
  const int brow = l >> 2;                                     // bf16: 16 rows/issue
  const int bcol = ((16 * (l & 3)) ^ ((brow & 3) << 4)) >> 1;  // bf16 elems

  const f32x4 fz = {0.f, 0.f, 0.f, 0.f};
  f32x4 acc[4][4];
#pragma unroll
  for (int i = 0; i < 4; i++)
#pragma unroll
    for (int j = 0; j < 4; j++) acc[i][j] = fz;

  for (int kk = 0; kk < K; kk += 32) {
    __syncthreads();   // previous iteration's LDS reads complete
    if constexpr (AF32) {
#pragma unroll
      for (int i = 0; i < 4; i++) {
        const float* gp = (const float*)Av + (m0 + w32 + i * 8 + arow) * (long)K + kk + acol;
        gload16(gp, &As[(w32 + i * 8) * 128]);
      }
    } else {
#pragma unroll
      for (int i = 0; i < 2; i++) {
        const ushort_t* gp = (const ushort_t*)Av + (m0 + w32 + i * 16 + brow) * (long)K + kk + bcol;
        gload16(gp, &As[(w32 + i * 16) * 64]);
      }
    }
#pragma unroll
    for (int i = 0; i < 2; i++) {
      const ushort_t* gp = Bt + (long)(n0 + w32 + i * 16 + brow) * K + kk + bcol;
      gload16(gp, &Bs[(w32 + i * 16) * 64]);
    }
    __syncthreads();   // vmcnt(0) drain + barrier: tile visible

    bf16x8 af[4], bfr[4];
    if constexpr (AF32) {
#pragma unroll
      for (int mi = 0; mi < 4; mi++) {
        const int aR = wr * 64 + mi * 16 + lrow;
        const int s = (aR & 7) << 4;
        const int c0 = g * 32;
        f32x4 x = *(const f32x4*)&As[aR * 128 + (c0 ^ s)];
        f32x4 y = *(const f32x4*)&As[aR * 128 + ((c0 + 16) ^ s)];
        union { unsigned int u[4]; bf16x8 v; } r;
        r.u[0] = cvtpk(x[0], x[1]);
        r.u[1] = cvtpk(x[2], x[3]);
        r.u[2] = cvtpk(y[0], y[1]);
        r.u[3] = cvtpk(y[2], y[3]);
        af[mi] = r.v;
      }
    } else {
#pragma unroll
      for (int mi = 0; mi < 4; mi++) {
        const int aR = wr * 64 + mi * 16 + lrow;
        af[mi] = *(const bf16x8*)&As[aR * 64 + ((g * 16) ^ ((aR & 3) << 4))];
      }
    }
#pragma unroll
    for (int ni = 0; ni < 4; ni++) {
      const int bR = wc * 64 + ni * 16 + lrow;
      bfr[ni] = *(const bf16x8*)&Bs[bR * 64 + ((g * 16) ^ ((bR & 3) << 4))];
    }
#pragma unroll
    for (int mi = 0; mi < 4; mi++)
#pragma unroll
      for (int ni = 0; ni < 4; ni++)
        acc[mi][ni] = MFMA16(af[mi], bfr[ni], acc[mi][ni]);
  }

#pragma unroll
  for (int mi = 0; mi < 4; mi++) {
    const long row0 = m0 + wr * 64 + mi * 16 + (l >> 4) * 4;
#pragma unroll
    for (int ni = 0; ni < 4; ni++) {
      const int col = n0 + wc * 64 + ni * 16 + lrow;
      const float bv = bias[col];
#pragma unroll
      for (int r = 0; r < 4; r++) {
        const float val = acc[mi][ni][r] + bv;
        if constexpr (CF32)
          ((float*)Cv)[(row0 + r) * N + col] = val;
        else
          ((ushort_t*)Cv)[(row0 + r) * N + col] = f2bf(val);
      }
    }
  }
}

// ---------------------------------------------------------------- attention
// Round-13 structure + T14 async-STAGE split for V: the V global loads are
// issued at kernel start (alongside K's gload16), held in registers through
// QK^T/softmax, and only the LDS writes happen after the softmax barrier.
// Removes the exposed post-softmax global round-trip. ~27 KB -> 6 blocks/CU.
__global__ __launch_bounds__(256, 1) void attn_k(const ushort_t* __restrict__ Qp,
                                                 const ushort_t* __restrict__ KVp,
                                                 const float* __restrict__ rpbt,
                                                 ushort_t* __restrict__ Ao) {
  __shared__ ushort_t P[64 * 136];                              // probabilities, bf16
  __shared__ __align__(16) unsigned char poolKV[32 * 136 * 2];  // Ks then Vt
  __shared__ float Ltab[225];                                   // rpb column for head
  ushort_t* Ks = (ushort_t*)poolKV;   // [128][32] u16 linear (8,192 B)
  ushort_t* Vt = (ushort_t*)poolKV;   // [32][136] u16 (8,704 B)
  const int t = threadIdx.x;
  const int l = t & 63;
  const int w = t >> 6;              // wave = owned mi block
  const int wnd = blockIdx.x;        // chunk-local (b, wh, ww)
  const int h = blockIdx.y;          // 0..15
  const int b = wnd >> 8;
  const int wh = (wnd >> 4) & 15;
  const int ww = wnd & 15;

  const int lrow = l & 15;
  const int lq = l >> 4;
  const int lk = lq * 8;

  auto qrow = [&](int q) -> long {
    int i = q >> 3, j = q & 7;
    int ho = (wh * 8 + i + 4) & 127;     // un-roll: rolled pos p <- orig p+shift
    int wo = (ww * 8 + j + 4) & 127;
    return (long)((b << 14) + (ho << 7) + wo);
  };
  auto kvrow = [&](int kp) -> long {
    int f = kp >> 6, m = kp & 63;
    int i = m >> 3, j = m & 7;
    int ho = (wh * 8 + i + 4) & 127;
    int wo = (ww * 8 + j + 4) & 127;
    return (long)(((b * 2 + f) << 14) + (ho << 7) + wo);
  };
  auto cnt_of = [&](int m) -> int {
    int hr = wh * 8 + (m >> 3), wr2 = ww * 8 + (m & 7);
    int rh = hr < 120 ? 0 : (hr < 124 ? 1 : 2);
    int rw = wr2 < 120 ? 0 : (wr2 < 124 ? 1 : 2);
    return rh * 3 + rw;
  };
  auto cvec = [](int m) -> int { return 15 * (m >> 3) + (m & 7); };

  // ---- stage K into LDS: wave w covers rows w*32..w*32+31 (2 issues)
#pragma unroll
  for (int i = 0; i < 2; i++) {
    const int row = w * 32 + i * 16 + (l >> 2);
    const ushort_t* gp = KVp + kvrow(row) * 1024 + h * 32 + (l & 3) * 8;
    gload16(gp, Ks + (w * 32 + i * 16) * 32);
  }
  // ---- T14: issue V global loads NOW (land during QK^T/softmax)
  const int vkp = t & 127;
  const int vdh = t >> 7;            // 0: d 0..15, 1: d 16..31
  const ushort_t* vsrc = KVp + kvrow(vkp) * 1024 + 512 + h * 32 + vdh * 16;
  bf16x8 v0 = *(const bf16x8*)(vsrc);
  bf16x8 v1 = *(const bf16x8*)(vsrc + 8);
  asm volatile("" :: "v"(v0), "v"(v1));   // keep issued early (rule #17)

  for (int i = t; i < 225; i += 256) Ltab[i] = rpbt[i * 16 + h];

  // ---- Q fragment (global, read once)
  bf16x8 af = *(const bf16x8*)(Qp + qrow(w * 16 + lrow) * 512 + h * 32 + lk);

  __syncthreads();  // K staged (vmcnt drained) + Ltab ready; V in regs

  // ---- QK^T for own row block, K from LDS
  const f32x4 fz = {0.f, 0.f, 0.f, 0.f};
  f32x4 s[8];
#pragma unroll
  for (int ni = 0; ni < 8; ni++) s[ni] = fz;
#pragma unroll
  for (int ni = 0; ni < 8; ni++) {
    bf16x8 kf = *(const bf16x8*)&Ks[(ni * 16 + lrow) * 32 + lk];
    s[ni] = MFMA16(af, kf, s[ni]);
  }

  // ---- scale + rpb + mask + wave-parallel softmax (16-lane groups own rows)
  const float scale = 0.17677669529663687f;  // 32^-0.5
#pragma unroll
  for (int r = 0; r < 4; r++) {
    const int q = w * 16 + lq * 4 + r;
    const int cq = cnt_of(q);
    const int cqv = cvec(q);
    float mx = -3.0e38f;
#pragma unroll
    for (int ni = 0; ni < 8; ni++) {
      const int k63 = (ni * 16 + lrow) & 63;
      float v = s[ni][r] * scale + Ltab[cqv + cvec(63 - k63)];
      if (cnt_of(k63) != cq) v -= 100.f;
      s[ni][r] = v;
      mx = fmaxf(mx, v);
    }
    mx = fmaxf(mx, __shfl_xor(mx, 1));
    mx = fmaxf(mx, __shfl_xor(mx, 2));
    mx = fmaxf(mx, __shfl_xor(mx, 4));
    mx = fmaxf(mx, __shfl_xor(mx, 8));
    float sum = 0.f;
#pragma unroll
    for (int ni = 0; ni < 8; ni++) {
      float p = __expf(s[ni][r] - mx);
      s[ni][r] = p;
      sum += p;
    }
    sum += __shfl_xor(sum, 1);
    sum += __shfl_xor(sum, 2);
    sum += __shfl_xor(sum, 4);
    sum += __shfl_xor(sum, 8);
    const float inv = 1.f / sum;
#pragma unroll
    for (int ni = 0; ni < 8; ni++)
      P[q * 136 + ni * 16 + lrow] = f2bf(s[ni][r] * inv);
  }

  __syncthreads();  // Ks + Ltab dead across ALL waves; pool reusable as Vt

  // ---- write V (already in regs) transposed: Vt[d][kvpos]
#pragma unroll
  for (int d = 0; d < 8; d++) {
    Vt[(vdh * 16 + d) * 136 + vkp] = (ushort_t)v0[d];
    Vt[(vdh * 16 + 8 + d) * 136 + vkp] = (ushort_t)v1[d];
  }
  __syncthreads();  // Vt ready (P own-rows need no barrier: self-written)

  // ---- PV for own row block: O[16x32] = P[16x128] @ V[128x32]
  f32x4 o[2] = {fz, fz};
#pragma unroll
  for (int ks = 0; ks < 4; ks++) {
    bf16x8 pf = *(const bf16x8*)&P[(w * 16 + lrow) * 136 + ks * 32 + lk];
#pragma unroll
    for (int ni = 0; ni < 2; ni++) {
      bf16x8 vf = *(const bf16x8*)&Vt[(ni * 16 + lrow) * 136 + ks * 32 + lk];
      o[ni] = MFMA16(pf, vf, o[ni]);
    }
  }

  // ---- write Ao (spatial order restored by qrow mapping)
#pragma unroll
  for (int ni = 0; ni < 2; ni++)
#pragma unroll
    for (int r = 0; r < 4; r++) {
      const int q = w * 16 + lq * 4 + r;
      Ao[qrow(q) * 512 + h * 32 + ni * 16 + lrow] = f2bf(o[ni][r]);
    }
}

// ---------------------------------------------------------------- launch
extern "C" void kernel_launch(void* const* d_in, const int* in_sizes, int n_in,
                              void* d_out, int out_size, void* d_ws, size_t ws_size,
                              hipStream_t stream) {
  (void)in_sizes; (void)n_in; (void)out_size;
  const float* q    = (const float*)d_in[0];   // f32 inputs
  const float* kv   = (const float*)d_in[1];
  // d_in[2], d_in[3] = H, W (constants 128, hardcoded)
  const float* rpbt = (const float*)d_in[4];
  const float* Wq   = (const float*)d_in[5];
  const float* bq   = (const float*)d_in[6];
  const float* Wkv  = (const float*)d_in[7];
  const float* bkv  = (const float*)d_in[8];
  const float* Wo   = (const float*)d_in[9];
  const float* bo   = (const float*)d_in[10];
  float* out = (float*)d_out;                  // f32 output

  const size_t QB  = 16384ULL * 512;    // Q/Ao elements per batch
  const size_t KVB = 32768ULL * 1024;   // projected KV elements per batch
  const size_t per_b_bytes = (QB + QB + KVB) * 2;   // bf16 scratch
  const size_t fixed_bytes = (512ULL*512 + 512ULL*1024 + 512ULL*512) * 2; // 2 MB
  const size_t needed1 = fixed_bytes + per_b_bytes;

  if (ws_size < needed1) {   // can't run: signal ws_size via out[0]
    ws_sentinel<<<dim3(1), 64, 0, stream>>>(out, (unsigned long long)ws_size);
    return;
  }

  int nbc = 8;
  while (nbc > 1 && fixed_bytes + (size_t)nbc * per_b_bytes > ws_size) nbc >>= 1;

  char* ws = (char*)d_ws;
  ushort_t* WqT  = (ushort_t*)ws;
  ushort_t* WkvT = WqT + 512 * 512;
  ushort_t* WoT  = WkvT + 512 * 1024;
  ushort_t* Qp   = (ushort_t*)(ws + fixed_bytes);
  ushort_t* Ao   = Qp + (size_t)nbc * QB;
  ushort_t* KVp  = Ao + (size_t)nbc * QB;

  wtrans3<<<dim3(4096), 256, 0, stream>>>(Wq, Wkv, Wo, WqT, WkvT, WoT);

  for (int c = 0; c < 8 / nbc; ++c) {
    const size_t b0 = (size_t)c * nbc;
    const int MtQ = nbc * 128;    // Q/Ao M-tiles, divisible by 8
    const int MtKV = nbc * 256;   // KV M-tiles, divisible by 8
    gemm_bt<true, false><<<dim3(MtQ * 4), 256, 0, stream>>>(q + b0 * QB, WqT, bq,
                                                            Qp, 512, 4);
    gemm_bt<true, false><<<dim3(MtKV * 8), 256, 0, stream>>>(kv + b0 * KVB / 2, WkvT,
                                                             bkv, KVp, 1024, 8);
    attn_k<<<dim3(nbc * 256, 16), 256, 0, stream>>>(Qp, KVp, rpbt, Ao);
    gemm_bt<false, true><<<dim3(MtQ * 4), 256, 0, stream>>>(Ao, WoT, bo,
                                                            out + b0 * QB, 512, 4);
  }
}